// Round 4
// baseline (553.909 us; speedup 1.0000x reference)
//
#include <hip/hip_runtime.h>

// LinearAttention: b=16, n=4096, dim=512, H=8, D=64, inner=512. T=65536 tokens.
// I/O dtype: fp32 (per reference). Compute: bf16 MFMA, fp32 accumulate.
// ws layout (~133.8 MiB):
//   wq_bf  [1536x512 bf16]  W_qkv converted + ROW-PERMUTED:
//            rows 0..511 = q; rows 512+h*128+[0..63] = k of head h;
//            rows 512+h*128+[64..127] = v of head h.
//   wo_bf  [ 512x512 bf16]  converted W_out
//   wsq    [65536x512 bf16] q' = act(x@Wq^T)  (read-only after gemm_qkv)
//   xb     [65536x512 bf16] x converted once
//   kvglob [128 x 64x80 f32] kv accumulator (atomicAdd), col e=64 = ksum
//   kvt    [128 x 80x64 bf16] kv transposed [e][d]; row 64 = ksum

typedef unsigned short u16;
typedef u16 u16x4 __attribute__((ext_vector_type(4)));
typedef u16 u16x8 __attribute__((ext_vector_type(8)));
typedef __bf16 bf16x8 __attribute__((ext_vector_type(8)));
typedef float f32x4 __attribute__((ext_vector_type(4)));

__device__ __forceinline__ u16 f2bf(float f) {
    union { float f; unsigned u; } t; t.f = f;
    unsigned r = t.u + 0x7fffu + ((t.u >> 16) & 1u);   // RNE
    return (u16)(r >> 16);
}
__device__ __forceinline__ float act_fn(float v) {     // 1 + elu
    return v > 0.0f ? v + 1.0f : __expf(v);
}
__device__ __forceinline__ void cvt8(const float* __restrict__ s, u16* __restrict__ d) {
    f32x4 lo = *(const f32x4*)s;
    f32x4 hi = *(const f32x4*)(s + 4);
    u16x8 o = { f2bf(lo[0]), f2bf(lo[1]), f2bf(lo[2]), f2bf(lo[3]),
                f2bf(hi[0]), f2bf(hi[1]), f2bf(hi[2]), f2bf(hi[3]) };
    *(u16x8*)d = o;
}
// async global->LDS, 16B per lane. LDS dest = wave-uniform base + lane*16.
__device__ __forceinline__ void gld16(const u16* g, u16* l) {
    __builtin_amdgcn_global_load_lds(
        (__attribute__((address_space(1))) const void*)g,
        (__attribute__((address_space(3))) void*)l, 16, 0, 0);
}

// ---------------------------------------------------------------------------
// convert_all: x (4,194,304 x8 units) -> xb ; W_qkv (98,304 units) -> wq_bf
// with the head-interleaved row permutation ; W_out (32,768) -> wo_bf ;
// zero kvglob (81,920 f32 = 10,240 x8 units). 17,216 x 256 exact.
// ---------------------------------------------------------------------------
__global__ __launch_bounds__(256) void convert_all(const float* __restrict__ x,
                                                   const float* __restrict__ Wqkv,
                                                   const float* __restrict__ Wout,
                                                   u16* __restrict__ xb,
                                                   u16* __restrict__ wq,
                                                   u16* __restrict__ wo,
                                                   float* __restrict__ kvg)
{
    size_t u = (size_t)blockIdx.x * 256 + threadIdx.x;
    if (u < 4194304ull) {
        cvt8(x + u * 8, xb + u * 8);
    } else if (u < 4292608ull) {
        u -= 4194304ull;                       // dest unit within wq_bf
        const int drow = (int)(u >> 6);
        int srow;
        if (drow < 512) srow = drow;
        else {
            const int t = drow - 512, h = t >> 7, j = t & 127;
            srow = (j < 64) ? (512 + h * 64 + j) : (1024 + h * 64 + (j - 64));
        }
        cvt8(Wqkv + (size_t)srow * 512 + (u & 63) * 8, wq + u * 8);
    } else if (u < 4325376ull) {
        u -= 4292608ull; cvt8(Wout + u * 8, wo + u * 8);
    } else {
        u -= 4325376ull;
        f32x4 z = { 0.f, 0.f, 0.f, 0.f };
        *(f32x4*)&kvg[u * 8] = z;
        *(f32x4*)&kvg[u * 8 + 4] = z;
    }
}

// ---------------------------------------------------------------------------
// gemm_qkv: C128x128 tile of x @ Wqkv_perm^T, K=512, 2-phase double-buffered
// global_load_lds staging. XCD-swizzled block remap (T1, cpx=768): the 12
// blocks sharing an x-tile land in the SAME XCD chunk -> L2-local re-reads.
// Col-tiles 0..3 -> q: act + store to wsq.  Col-tiles 4..11 -> head h=nt-4:
// cols 0..63 = k, 64..127 = v; transpose to KT/VT (overlaying the dead LDS
// double buffer), kv[d][e] += KT@VT^T (VT row 64 = ones -> e=64 = ksum),
// atomicAdd into kvglob[b*8+h].
// ---------------------------------------------------------------------------
__global__ __launch_bounds__(256) void gemm_qkv(const u16* __restrict__ A,
                                                const u16* __restrict__ Bw,
                                                u16* __restrict__ Cq,
                                                float* __restrict__ kvglob)
{
    __shared__ u16 SMF[16384];     // 32 KB: buf b at b*8192 (As 4096 | Bs 4096)
    const int id = blockIdx.y * 12 + blockIdx.x;        // 6144 blocks
    const int o  = (id & 7) * 768 + (id >> 3);          // bijective XCD chunks
    const int nt = o % 12;         // col-tile
    const int mt = o / 12;         // M-tile
    const size_t row0 = (size_t)mt * 128;
    const int col0 = nt * 128;
    const int tid = threadIdx.x, wave = tid >> 6, lane = tid & 63;
    const int frow = lane & 15, quad = lane >> 4;
    const int wr = (wave >> 1) * 64, wc = (wave & 1) * 64;

    f32x4 acc[4][4] = {};

    // staging: chunk ch = issue*256 + wave*64 + lane; row = ch>>2, col=(ch&3)*8
    const int ch0 = wave * 64 + lane, ch1 = 256 + ch0;
    const int r0 = ch0 >> 2, c0 = (ch0 & 3) * 8;
    const int r1 = ch1 >> 2, c1 = (ch1 & 3) * 8;
    const u16* gA0 = A + (row0 + r0) * 512 + c0;
    const u16* gA1 = A + (row0 + r1) * 512 + c1;
    const u16* gB0 = Bw + (size_t)(col0 + r0) * 512 + c0;
    const u16* gB1 = Bw + (size_t)(col0 + r1) * 512 + c1;

#define QKV_STAGE(buf, k0) do {                                   \
        u16* As_ = SMF + (buf) * 8192;                            \
        u16* Bs_ = As_ + 4096;                                    \
        gld16(gA0 + (k0), As_ + wave * 512);                      \
        gld16(gA1 + (k0), As_ + 2048 + wave * 512);               \
        gld16(gB0 + (k0), Bs_ + wave * 512);                      \
        gld16(gB1 + (k0), Bs_ + 2048 + wave * 512);               \
    } while (0)

    QKV_STAGE(0, 0);
    __syncthreads();               // implicit vmcnt(0): buf0 ready
    int cur = 0;
    for (int t = 0; t < 16; ++t) {
        if (t < 15) QKV_STAGE(cur ^ 1, (t + 1) * 32);   // prefetch next tile
        const u16* As_ = SMF + cur * 8192;
        const u16* Bs_ = As_ + 4096;
        bf16x8 af[4], bfr[4];
#pragma unroll
        for (int mi = 0; mi < 4; ++mi)
            af[mi] = *(const bf16x8*)&As_[(wr + mi * 16 + frow) * 32 + quad * 8];
#pragma unroll
        for (int ni = 0; ni < 4; ++ni)
            bfr[ni] = *(const bf16x8*)&Bs_[(wc + ni * 16 + frow) * 32 + quad * 8];
#pragma unroll
        for (int mi = 0; mi < 4; ++mi)
#pragma unroll
            for (int ni = 0; ni < 4; ++ni)
                acc[mi][ni] = __builtin_amdgcn_mfma_f32_16x16x32_bf16(af[mi], bfr[ni], acc[mi][ni], 0, 0, 0);
        __syncthreads();           // drains vmcnt(0): prefetched buf ready
        cur ^= 1;
    }
#undef QKV_STAGE

    if (col0 < 512) {
        // q epilogue: C/D layout col = lane&15, row = quad*4 + reg [m89/m91]
#pragma unroll
        for (int mi = 0; mi < 4; ++mi) {
#pragma unroll
            for (int ni = 0; ni < 4; ++ni) {
                const int c = col0 + wc + ni * 16 + frow;
                const size_t rbase = row0 + wr + mi * 16 + quad * 4;
#pragma unroll
                for (int reg = 0; reg < 4; ++reg)
                    Cq[(rbase + reg) * 512 + c] = f2bf(act_fn(acc[mi][ni][reg]));
            }
        }
        return;
    }

    // ---- kv epilogue (head h = nt-4), KT/VT overlay the dead double buffer
    u16* KT = SMF;                 // [64][72] k^T
    u16* VT = SMF + 4608;          // [80][72] v^T; row 64 = ones
    for (int i = tid; i < 16 * 72; i += 256)
        VT[64 * 72 + i] = (i < 64) ? (u16)0x3F80 : (u16)0;

    const bool is_k = (wc == 0);
    f32x4 kvacc[5] = {};           // e-tiles; d = wave*16 + quad*4 + reg

#pragma unroll
    for (int half = 0; half < 2; ++half) {
        __syncthreads();           // prior KT/VT readers (and ones writes) done
        if ((wave >> 1) == half) { // this wave's tokens belong to this half
#pragma unroll
            for (int mi = 0; mi < 4; ++mi) {
                const int n0 = wr + mi * 16 + quad * 4 - half * 64;   // 0..60
#pragma unroll
                for (int ni = 0; ni < 4; ++ni) {
                    const int cl = wc + ni * 16 + frow;               // 0..127
                    u16x4 o2;
#pragma unroll
                    for (int reg = 0; reg < 4; ++reg) {
                        float v = acc[mi][ni][reg];
                        if (is_k) v = act_fn(v);
                        o2[reg] = f2bf(v);
                    }
                    if (is_k) *(u16x4*)&KT[cl * 72 + n0] = o2;
                    else      *(u16x4*)&VT[(cl - 64) * 72 + n0] = o2;
                }
            }
        }
        __syncthreads();
        // kv[d][e] += KT@VT^T over this half's 64 tokens (2 K-chunks of 32)
#pragma unroll
        for (int c = 0; c < 2; ++c) {
            bf16x8 af2 = *(const bf16x8*)&KT[(wave * 16 + frow) * 72 + c * 32 + quad * 8];
#pragma unroll
            for (int et = 0; et < 5; ++et) {
                bf16x8 bf2 = *(const bf16x8*)&VT[(et * 16 + frow) * 72 + c * 32 + quad * 8];
                kvacc[et] = __builtin_amdgcn_mfma_f32_16x16x32_bf16(af2, bf2, kvacc[et], 0, 0, 0);
            }
        }
    }

    const int b = mt >> 5, h = nt - 4;
    float* dst = kvglob + (size_t)(b * 8 + h) * 5120;
#pragma unroll
    for (int et = 0; et < 5; ++et) {
        const int e = et * 16 + frow;
        if (e <= 64) {
#pragma unroll
            for (int reg = 0; reg < 4; ++reg) {
                const int d = wave * 16 + quad * 4 + reg;
                atomicAdd(&dst[d * 80 + e], kvacc[et][reg]);
            }
        }
    }
}

// kvt[bh][e][d] bf16: transpose of kvglob[bh][d][e]; e rows 65..79 zero.
__global__ __launch_bounds__(256) void reduce_kvt(const float* __restrict__ kvglob,
                                                  u16* __restrict__ kvt)
{
    const int bh = blockIdx.x, tid = threadIdx.x;
    for (int i = tid; i < 5120; i += 256) {
        const int e = i >> 6, d = i & 63;
        kvt[(size_t)bh * 5120 + i] =
            (e < 65) ? f2bf(kvglob[(size_t)bh * 5120 + d * 80 + e]) : (u16)0;
    }
}

// ---------------------------------------------------------------------------
// fused_out: attention-apply fused into the output GEMM — attn never touches
// HBM. Per block: 128 tokens x 128 out-cols. Loop h=0..7 (each head = K-chunk
// of 64 in the out GEMM):
//  (a) attnT[e][tok] = kvt_h @ q'^T by MFMA (verified apply_attn inner);
//      row e=64 -> denominator, shfl-broadcast, z = 1/max(den,eps);
//  (b) scaled attn tile -> LDS attnL[128][72] (pad 72: 2-way = free);
//  (c) oacc += attnL(128x64) @ Wout^T fragments read DIRECT from global
//      (wo_bf 512 KB, L2-resident — no LDS staging needed).
// XCD-swizzled (cpx=256) so the 4 col-blocks sharing a token tile share L2.
// ---------------------------------------------------------------------------
__global__ __launch_bounds__(256) void fused_out(const u16* __restrict__ Q,
                                                 const u16* __restrict__ kvt,
                                                 const u16* __restrict__ Bw,
                                                 float* __restrict__ C,
                                                 const float* __restrict__ bias)
{
    __shared__ u16 attnL[128 * 72];
    const int id = blockIdx.y * 4 + blockIdx.x;         // 2048 blocks
    const int o  = (id & 7) * 256 + (id >> 3);          // bijective XCD chunks
    const int nt = o & 3, mt = o >> 2;
    const size_t t0 = (size_t)mt * 128;
    const int col0 = nt * 128;
    const int bb = mt >> 5;                             // batch
    const int tid = threadIdx.x, wave = tid >> 6, lane = tid & 63;
    const int frow = lane & 15, quad = lane >> 4;
    const int wt = wave * 32;                           // attn: wave owns 32 tok
    const int wr = (wave >> 1) * 64, wc = (wave & 1) * 64;  // out quadrant

    f32x4 oacc[4][4] = {};

    for (int h = 0; h < 8; ++h) {
        const u16* kvh = kvt + (size_t)(bb * 8 + h) * 5120;
        // (a) attnT: acc[mi][ni] — e-tile(80) x tok-tile(32); col=tok, row=e
        f32x4 acc[5][2] = {};
#pragma unroll
        for (int kc = 0; kc < 2; ++kc) {      // d = kc*32 + quad*8 + j
            bf16x8 bfr[2];
#pragma unroll
            for (int ni = 0; ni < 2; ++ni)
                bfr[ni] = *(const bf16x8*)&Q[(t0 + wt + ni * 16 + frow) * 512 + h * 64 + kc * 32 + quad * 8];
#pragma unroll
            for (int mi = 0; mi < 5; ++mi) {
                bf16x8 afr = *(const bf16x8*)&kvh[(mi * 16 + frow) * 64 + kc * 32 + quad * 8];
#pragma unroll
                for (int ni = 0; ni < 2; ++ni)
                    acc[mi][ni] = __builtin_amdgcn_mfma_f32_16x16x32_bf16(afr, bfr[ni], acc[mi][ni], 0, 0, 0);
            }
        }
        __syncthreads();           // prev h's attnL reads complete
        // (b) z-scale and store attn[tok][e] to LDS
#pragma unroll
        for (int ni = 0; ni < 2; ++ni) {
            // den(tok) sits in row e=64: lanes quad==0, reg 0, col=tok&15
            const float den = __shfl(acc[4][ni][0], frow, 64);
            const float z = 1.0f / fmaxf(den, 1e-4f);
            const int tok = wt + ni * 16 + frow;
#pragma unroll
            for (int mi = 0; mi < 4; ++mi) {
                u16x4 t;
#pragma unroll
                for (int reg = 0; reg < 4; ++reg) t[reg] = f2bf(acc[mi][ni][reg] * z);
                *(u16x4*)&attnL[tok * 72 + mi * 16 + quad * 4] = t;
            }
        }
        __syncthreads();           // attnL ready
        // (c) out GEMM over this head's K-chunk of 64
#pragma unroll
        for (int kk = 0; kk < 2; ++kk) {
            bf16x8 af[4], bfr2[4];
#pragma unroll
            for (int mi = 0; mi < 4; ++mi)
                af[mi] = *(const bf16x8*)&attnL[(wr + mi * 16 + frow) * 72 + kk * 32 + quad * 8];
#pragma unroll
            for (int ni = 0; ni < 4; ++ni)
                bfr2[ni] = *(const bf16x8*)&Bw[(size_t)(col0 + wc + ni * 16 + frow) * 512 + h * 64 + kk * 32 + quad * 8];
#pragma unroll
            for (int mi = 0; mi < 4; ++mi)
#pragma unroll
                for (int ni = 0; ni < 4; ++ni)
                    oacc[mi][ni] = __builtin_amdgcn_mfma_f32_16x16x32_bf16(af[mi], bfr2[ni], oacc[mi][ni], 0, 0, 0);
        }
    }

    // epilogue: C/D layout col = lane&15, row = quad*4 + reg
#pragma unroll
    for (int mi = 0; mi < 4; ++mi) {
#pragma unroll
        for (int ni = 0; ni < 4; ++ni) {
            const int c = col0 + wc + ni * 16 + frow;
            const float bv = bias[c];
            const size_t rbase = t0 + wr + mi * 16 + quad * 4;
#pragma unroll
            for (int reg = 0; reg < 4; ++reg)
                C[(rbase + reg) * 512 + c] = oacc[mi][ni][reg] + bv;
        }
    }
}

extern "C" void kernel_launch(void* const* d_in, const int* in_sizes, int n_in,
                              void* d_out, int out_size, void* d_ws, size_t ws_size,
                              hipStream_t stream)
{
    const float* x    = (const float*)d_in[0];   // [65536, 512] fp32
    const float* Wqkv = (const float*)d_in[1];   // [1536, 512]  fp32
    const float* Wout = (const float*)d_in[2];   // [512, 512]   fp32
    const float* bout = (const float*)d_in[3];   // [512]        fp32
    float* out = (float*)d_out;                  // [65536, 512] fp32
    char* ws = (char*)d_ws;

    u16*   wq_bf  = (u16*)ws;                      //   1,572,864 B
    u16*   wo_bf  = (u16*)(ws + 1572864ull);       //     524,288 B
    u16*   wsq    = (u16*)(ws + 2097152ull);       //  67,108,864 B
    u16*   xb     = (u16*)(ws + 69206016ull);      //  67,108,864 B
    float* kvglob = (float*)(ws + 136314880ull);   //   2,621,440 B
    u16*   kvt    = (u16*)(ws + 138936320ull);     //   1,310,720 B -> 140,247,040

    // 0) x -> bf16, weights -> bf16 (W_qkv row-permuted), zero kv accumulator
    convert_all<<<17216, 256, 0, stream>>>(x, Wqkv, Wout, xb, wq_bf, wo_bf, kvglob);
    // 1) fused qkv GEMM: q' -> wsq ; per-head kv outer-product -> kvglob
    gemm_qkv<<<dim3(12, 512), 256, 0, stream>>>(xb, wq_bf, wsq, kvglob);
    // 2) transpose -> bf16 kvt (row e=64 = ksum)
    reduce_kvt<<<128, 256, 0, stream>>>(kvglob, kvt);
    // 3) attention-apply + output GEMM fused: out = (q'·kv·z) @ Wout^T + b
    fused_out<<<dim3(4, 512), 256, 0, stream>>>(wsq, kvt, wo_bf, out, bout);
}

// Round 5
// 508.944 us; speedup vs baseline: 1.0883x; 1.0883x over previous
//
#include <hip/hip_runtime.h>

// LinearAttention: b=16, n=4096, dim=512, H=8, D=64, inner=512. T=65536 tokens.
// I/O dtype: fp32 (per reference). Compute: bf16 MFMA, fp32 accumulate.
//
// Algebraic refactor: out[t] = sum_h z_h(t) * (q'_h[t] @ kv_h) @ Wout_h
//                            = (z .* q') @ Pcat,   Pcat_b[c][h*64+d] = sum_e kv_h[d][e] Wout[c][h*64+e]
// so the attention apply is a scalar row-scale (apply_z) + one plain GEMM.
//
// ws layout (~139 MiB):
//   wq_bf  [1536x512 bf16]  W_qkv converted + ROW-PERMUTED:
//            rows 0..511 = q; rows 512+h*128+[0..63] = k of head h;
//            rows 512+h*128+[64..127] = v of head h.
//   wo_bf  [ 512x512 bf16]  converted W_out
//   wsq    [65536x512 bf16] q' = act(x@Wq^T); scaled in place by apply_z
//   xb     [65536x512 bf16] x converted once; REUSED as P after gemm_qkv
//   kvglob [128 x 64x80 f32] kv accumulator (atomicAdd), col e=64 = ksum
//   ksum_bf[128 x 64 bf16]  per-(b,h) k-sum vector

typedef unsigned short u16;
typedef u16 u16x4 __attribute__((ext_vector_type(4)));
typedef u16 u16x8 __attribute__((ext_vector_type(8)));
typedef __bf16 bf16x8 __attribute__((ext_vector_type(8)));
typedef float f32x4 __attribute__((ext_vector_type(4)));

__device__ __forceinline__ float bf2f(u16 x) {
    union { unsigned u; float f; } t; t.u = ((unsigned)x) << 16; return t.f;
}
__device__ __forceinline__ u16 f2bf(float f) {
    union { float f; unsigned u; } t; t.f = f;
    unsigned r = t.u + 0x7fffu + ((t.u >> 16) & 1u);   // RNE
    return (u16)(r >> 16);
}
__device__ __forceinline__ float act_fn(float v) {     // 1 + elu
    return v > 0.0f ? v + 1.0f : __expf(v);
}
__device__ __forceinline__ void cvt8(const float* __restrict__ s, u16* __restrict__ d) {
    f32x4 lo = *(const f32x4*)s;
    f32x4 hi = *(const f32x4*)(s + 4);
    u16x8 o = { f2bf(lo[0]), f2bf(lo[1]), f2bf(lo[2]), f2bf(lo[3]),
                f2bf(hi[0]), f2bf(hi[1]), f2bf(hi[2]), f2bf(hi[3]) };
    *(u16x8*)d = o;
}
// async global->LDS, 16B per lane. LDS dest = wave-uniform base + lane*16.
__device__ __forceinline__ void gld16(const u16* g, u16* l) {
    __builtin_amdgcn_global_load_lds(
        (__attribute__((address_space(1))) const void*)g,
        (__attribute__((address_space(3))) void*)l, 16, 0, 0);
}

// ---------------------------------------------------------------------------
// convert_all: x (4,194,304 x8 units) -> xb ; W_qkv (98,304 units) -> wq_bf
// with the head-interleaved row permutation ; W_out (32,768) -> wo_bf ;
// zero kvglob (81,920 f32 = 10,240 x8 units). 17,216 x 256 exact.
// ---------------------------------------------------------------------------
__global__ __launch_bounds__(256) void convert_all(const float* __restrict__ x,
                                                   const float* __restrict__ Wqkv,
                                                   const float* __restrict__ Wout,
                                                   u16* __restrict__ xb,
                                                   u16* __restrict__ wq,
                                                   u16* __restrict__ wo,
                                                   float* __restrict__ kvg)
{
    size_t u = (size_t)blockIdx.x * 256 + threadIdx.x;
    if (u < 4194304ull) {
        cvt8(x + u * 8, xb + u * 8);
    } else if (u < 4292608ull) {
        u -= 4194304ull;                       // dest unit within wq_bf
        const int drow = (int)(u >> 6);
        int srow;
        if (drow < 512) srow = drow;
        else {
            const int t = drow - 512, h = t >> 7, j = t & 127;
            srow = (j < 64) ? (512 + h * 64 + j) : (1024 + h * 64 + (j - 64));
        }
        cvt8(Wqkv + (size_t)srow * 512 + (u & 63) * 8, wq + u * 8);
    } else if (u < 4325376ull) {
        u -= 4292608ull; cvt8(Wout + u * 8, wo + u * 8);
    } else {
        u -= 4325376ull;
        f32x4 z = { 0.f, 0.f, 0.f, 0.f };
        *(f32x4*)&kvg[u * 8] = z;
        *(f32x4*)&kvg[u * 8 + 4] = z;
    }
}

// ---------------------------------------------------------------------------
// gemm_qkv: C128x128 tile of x @ Wqkv_perm^T, K=512, 2-phase double-buffered
// global_load_lds staging. (R3 block mapping — the R4 XCD swizzle regressed.)
// Col-tiles 0..3 -> q: act + store to wsq.  Col-tiles 4..11 -> head h=nt-4:
// cols 0..63 = k, 64..127 = v; transpose to KT/VT (overlaying the dead LDS
// double buffer), kv[d][e] += KT@VT^T (VT row 64 = ones -> e=64 = ksum),
// atomicAdd into kvglob[b*8+h].
// ---------------------------------------------------------------------------
__global__ __launch_bounds__(256) void gemm_qkv(const u16* __restrict__ A,
                                                const u16* __restrict__ Bw,
                                                u16* __restrict__ Cq,
                                                float* __restrict__ kvglob)
{
    __shared__ u16 SMF[16384];     // 32 KB: buf b at b*8192 (As 4096 | Bs 4096)
    const int nt = blockIdx.x;     // 0..11 col-tile
    const int mt = blockIdx.y;     // 0..511 M-tile
    const size_t row0 = (size_t)mt * 128;
    const int col0 = nt * 128;
    const int tid = threadIdx.x, wave = tid >> 6, lane = tid & 63;
    const int frow = lane & 15, quad = lane >> 4;
    const int wr = (wave >> 1) * 64, wc = (wave & 1) * 64;

    f32x4 acc[4][4] = {};

    // staging: chunk ch = issue*256 + wave*64 + lane; row = ch>>2, col=(ch&3)*8
    const int ch0 = wave * 64 + lane, ch1 = 256 + ch0;
    const int r0 = ch0 >> 2, c0 = (ch0 & 3) * 8;
    const int r1 = ch1 >> 2, c1 = (ch1 & 3) * 8;
    const u16* gA0 = A + (row0 + r0) * 512 + c0;
    const u16* gA1 = A + (row0 + r1) * 512 + c1;
    const u16* gB0 = Bw + (size_t)(col0 + r0) * 512 + c0;
    const u16* gB1 = Bw + (size_t)(col0 + r1) * 512 + c1;

#define QKV_STAGE(buf, k0) do {                                   \
        u16* As_ = SMF + (buf) * 8192;                            \
        u16* Bs_ = As_ + 4096;                                    \
        gld16(gA0 + (k0), As_ + wave * 512);                      \
        gld16(gA1 + (k0), As_ + 2048 + wave * 512);               \
        gld16(gB0 + (k0), Bs_ + wave * 512);                      \
        gld16(gB1 + (k0), Bs_ + 2048 + wave * 512);               \
    } while (0)

    QKV_STAGE(0, 0);
    __syncthreads();               // implicit vmcnt(0): buf0 ready
    int cur = 0;
    for (int t = 0; t < 16; ++t) {
        if (t < 15) QKV_STAGE(cur ^ 1, (t + 1) * 32);   // prefetch next tile
        const u16* As_ = SMF + cur * 8192;
        const u16* Bs_ = As_ + 4096;
        bf16x8 af[4], bfr[4];
#pragma unroll
        for (int mi = 0; mi < 4; ++mi)
            af[mi] = *(const bf16x8*)&As_[(wr + mi * 16 + frow) * 32 + quad * 8];
#pragma unroll
        for (int ni = 0; ni < 4; ++ni)
            bfr[ni] = *(const bf16x8*)&Bs_[(wc + ni * 16 + frow) * 32 + quad * 8];
#pragma unroll
        for (int mi = 0; mi < 4; ++mi)
#pragma unroll
            for (int ni = 0; ni < 4; ++ni)
                acc[mi][ni] = __builtin_amdgcn_mfma_f32_16x16x32_bf16(af[mi], bfr[ni], acc[mi][ni], 0, 0, 0);
        __syncthreads();           // drains vmcnt(0): prefetched buf ready
        cur ^= 1;
    }
#undef QKV_STAGE

    if (col0 < 512) {
        // q epilogue: C/D layout col = lane&15, row = quad*4 + reg [m89/m91]
#pragma unroll
        for (int mi = 0; mi < 4; ++mi) {
#pragma unroll
            for (int ni = 0; ni < 4; ++ni) {
                const int c = col0 + wc + ni * 16 + frow;
                const size_t rbase = row0 + wr + mi * 16 + quad * 4;
#pragma unroll
                for (int reg = 0; reg < 4; ++reg)
                    Cq[(rbase + reg) * 512 + c] = f2bf(act_fn(acc[mi][ni][reg]));
            }
        }
        return;
    }

    // ---- kv epilogue (head h = nt-4), KT/VT overlay the dead double buffer
    u16* KT = SMF;                 // [64][72] k^T
    u16* VT = SMF + 4608;          // [80][72] v^T; row 64 = ones
    for (int i = tid; i < 16 * 72; i += 256)
        VT[64 * 72 + i] = (i < 64) ? (u16)0x3F80 : (u16)0;

    const bool is_k = (wc == 0);
    f32x4 kvacc[5] = {};           // e-tiles; d = wave*16 + quad*4 + reg

#pragma unroll
    for (int half = 0; half < 2; ++half) {
        __syncthreads();           // prior KT/VT readers (and ones writes) done
        if ((wave >> 1) == half) { // this wave's tokens belong to this half
#pragma unroll
            for (int mi = 0; mi < 4; ++mi) {
                const int n0 = wr + mi * 16 + quad * 4 - half * 64;   // 0..60
#pragma unroll
                for (int ni = 0; ni < 4; ++ni) {
                    const int cl = wc + ni * 16 + frow;               // 0..127
                    u16x4 o2;
#pragma unroll
                    for (int reg = 0; reg < 4; ++reg) {
                        float v = acc[mi][ni][reg];
                        if (is_k) v = act_fn(v);
                        o2[reg] = f2bf(v);
                    }
                    if (is_k) *(u16x4*)&KT[cl * 72 + n0] = o2;
                    else      *(u16x4*)&VT[(cl - 64) * 72 + n0] = o2;
                }
            }
        }
        __syncthreads();
        // kv[d][e] += KT@VT^T over this half's 64 tokens (2 K-chunks of 32)
#pragma unroll
        for (int c = 0; c < 2; ++c) {
            bf16x8 af2 = *(const bf16x8*)&KT[(wave * 16 + frow) * 72 + c * 32 + quad * 8];
#pragma unroll
            for (int et = 0; et < 5; ++et) {
                bf16x8 bf2 = *(const bf16x8*)&VT[(et * 16 + frow) * 72 + c * 32 + quad * 8];
                kvacc[et] = __builtin_amdgcn_mfma_f32_16x16x32_bf16(af2, bf2, kvacc[et], 0, 0, 0);
            }
        }
    }

    const int b = mt >> 5, h = nt - 4;
    float* dst = kvglob + (size_t)(b * 8 + h) * 5120;
#pragma unroll
    for (int et = 0; et < 5; ++et) {
        const int e = et * 16 + frow;
        if (e <= 64) {
#pragma unroll
            for (int reg = 0; reg < 4; ++reg) {
                const int d = wave * 16 + quad * 4 + reg;
                atomicAdd(&dst[d * 80 + e], kvacc[et][reg]);
            }
        }
    }
}

// ---------------------------------------------------------------------------
// make_P: one block per (b,h). P_b[c][h*64+d] = sum_e Wout[c][h*64+e]*kv[d][e]
// via MFMA (A = Wout rows from global, L2-resident; B = kv rows from LDS).
// Also extracts ksum_bf[bh][d] = kvglob col e=64. 512x64x64 GEMM per block.
// ---------------------------------------------------------------------------
__global__ __launch_bounds__(256) void make_P(const float* __restrict__ kvglob,
                                              const u16* __restrict__ wo,
                                              u16* __restrict__ P,
                                              u16* __restrict__ ksum)
{
    __shared__ u16 kvb[64 * 72];   // kv[d][e] bf16, pad 72
    const int bh = blockIdx.x, b = bh >> 3, h = bh & 7;
    const int tid = threadIdx.x, wave = tid >> 6, lane = tid & 63;
    const int frow = lane & 15, quad = lane >> 4;
    const float* src = kvglob + (size_t)bh * 5120;

    for (int i = tid; i < 4096; i += 256)
        kvb[(i >> 6) * 72 + (i & 63)] = f2bf(src[(i >> 6) * 80 + (i & 63)]);
    if (tid < 64) ksum[bh * 64 + tid] = f2bf(src[tid * 80 + 64]);
    __syncthreads();

    f32x4 acc[8][4] = {};          // m = Wout-row tile (wave*128..+128), n = d
    const int m0 = wave * 128;
#pragma unroll
    for (int k2 = 0; k2 < 2; ++k2) {           // e-chunk of 32
        bf16x8 bfr[4];
#pragma unroll
        for (int ni = 0; ni < 4; ++ni)
            bfr[ni] = *(const bf16x8*)&kvb[(ni * 16 + frow) * 72 + k2 * 32 + quad * 8];
#pragma unroll
        for (int mi = 0; mi < 8; ++mi) {
            bf16x8 af = *(const bf16x8*)&wo[(size_t)(m0 + mi * 16 + frow) * 512 + h * 64 + k2 * 32 + quad * 8];
#pragma unroll
            for (int ni = 0; ni < 4; ++ni)
                acc[mi][ni] = __builtin_amdgcn_mfma_f32_16x16x32_bf16(af, bfr[ni], acc[mi][ni], 0, 0, 0);
        }
    }

    u16* Pb = P + (size_t)b * 262144;
#pragma unroll
    for (int mi = 0; mi < 8; ++mi) {
#pragma unroll
        for (int ni = 0; ni < 4; ++ni) {
            const int d = ni * 16 + frow;      // C/D: col = lane&15
#pragma unroll
            for (int reg = 0; reg < 4; ++reg) {
                const int c = m0 + mi * 16 + quad * 4 + reg;
                Pb[(size_t)c * 512 + h * 64 + d] = f2bf(acc[mi][ni][reg]);
            }
        }
    }
}

// ---------------------------------------------------------------------------
// apply_z: q''[t][i] = q'[t][i] / max(q'_h(t)·ksum_h, eps), h = i/64.
// In place on wsq. Thread owns (token, 128-col quarter): 16 bf16x8 loads kept
// in regs for the scale pass; ksum reads are L2-hot. 1024 x 256.
// ---------------------------------------------------------------------------
__global__ __launch_bounds__(256) void apply_z(u16* __restrict__ qio,
                                               const u16* __restrict__ ksum)
{
    const int g = blockIdx.x * 256 + threadIdx.x;   // 262144 threads
    const int tok = g >> 2, p = g & 3;              // heads 2p, 2p+1
    const int b = tok >> 12;
    u16* qrow = qio + (size_t)tok * 512 + p * 128;
    const u16* ks = ksum + b * 512 + p * 128;

    u16x8 q[16];
    float den[2] = { 0.f, 0.f };
#pragma unroll
    for (int half = 0; half < 2; ++half) {
#pragma unroll
        for (int jj = 0; jj < 8; ++jj) {
            const int idx = half * 8 + jj;
            q[idx] = *(const u16x8*)&qrow[idx * 8];
            u16x8 k8 = *(const u16x8*)&ks[idx * 8];
#pragma unroll
            for (int e = 0; e < 8; ++e)
                den[half] += bf2f(q[idx][e]) * bf2f(k8[e]);
        }
    }
    const float z0 = 1.0f / fmaxf(den[0], 1e-4f);
    const float z1 = 1.0f / fmaxf(den[1], 1e-4f);
#pragma unroll
    for (int half = 0; half < 2; ++half) {
        const float z = half ? z1 : z0;
#pragma unroll
        for (int jj = 0; jj < 8; ++jj) {
            const int idx = half * 8 + jj;
            u16x8 o;
#pragma unroll
            for (int e = 0; e < 8; ++e) o[e] = f2bf(bf2f(q[idx][e]) * z);
            *(u16x8*)&qrow[idx * 8] = o;
        }
    }
}

// ---------------------------------------------------------------------------
// gemm_final: out[t][c] (fp32) = sum_i q''[t][i] * P_b[c][i] + bias[c].
// B matrix is per-batch (b = mt>>5), 512 KB, L2-resident. 2-phase dbuf
// global_load_lds staging (verified gemm_out structure).
// ---------------------------------------------------------------------------
__global__ __launch_bounds__(256) void gemm_final(const u16* __restrict__ A,
                                                  const u16* __restrict__ P,
                                                  float* __restrict__ C,
                                                  const float* __restrict__ bias)
{
    __shared__ u16 SMF[16384];
    const int nt = blockIdx.x;     // 0..3 col-tile
    const int mt = blockIdx.y;     // 0..511 M-tile
    const size_t row0 = (size_t)mt * 128;
    const int col0 = nt * 128;
    const u16* Bw = P + (size_t)(mt >> 5) * 262144;
    const int tid  = threadIdx.x;
    const int wave = tid >> 6, lane = tid & 63;
    const int wr = (wave >> 1) * 64, wc = (wave & 1) * 64;
    const int frow = lane & 15, quad = lane >> 4;

    f32x4 acc[4][4] = {};

    const int ch0 = wave * 64 + lane, ch1 = 256 + ch0;
    const int r0 = ch0 >> 2, c0 = (ch0 & 3) * 8;
    const int r1 = ch1 >> 2, c1 = (ch1 & 3) * 8;
    const u16* gA0 = A + (row0 + r0) * 512 + c0;
    const u16* gA1 = A + (row0 + r1) * 512 + c1;
    const u16* gB0 = Bw + (size_t)(col0 + r0) * 512 + c0;
    const u16* gB1 = Bw + (size_t)(col0 + r1) * 512 + c1;

#define OUT_STAGE(buf, k0) do {                                   \
        u16* As_ = SMF + (buf) * 8192;                            \
        u16* Bs_ = As_ + 4096;                                    \
        gld16(gA0 + (k0), As_ + wave * 512);                      \
        gld16(gA1 + (k0), As_ + 2048 + wave * 512);               \
        gld16(gB0 + (k0), Bs_ + wave * 512);                      \
        gld16(gB1 + (k0), Bs_ + 2048 + wave * 512);               \
    } while (0)

    OUT_STAGE(0, 0);
    __syncthreads();
    int cur = 0;
    for (int t = 0; t < 16; ++t) {
        if (t < 15) OUT_STAGE(cur ^ 1, (t + 1) * 32);
        const u16* As_ = SMF + cur * 8192;
        const u16* Bs_ = As_ + 4096;
        bf16x8 af[4], bfr[4];
#pragma unroll
        for (int mi = 0; mi < 4; ++mi)
            af[mi] = *(const bf16x8*)&As_[(wr + mi * 16 + frow) * 32 + quad * 8];
#pragma unroll
        for (int ni = 0; ni < 4; ++ni)
            bfr[ni] = *(const bf16x8*)&Bs_[(wc + ni * 16 + frow) * 32 + quad * 8];
#pragma unroll
        for (int mi = 0; mi < 4; ++mi)
#pragma unroll
            for (int ni = 0; ni < 4; ++ni)
                acc[mi][ni] = __builtin_amdgcn_mfma_f32_16x16x32_bf16(af[mi], bfr[ni], acc[mi][ni], 0, 0, 0);
        __syncthreads();
        cur ^= 1;
    }
#undef OUT_STAGE

#pragma unroll
    for (int mi = 0; mi < 4; ++mi) {
#pragma unroll
        for (int ni = 0; ni < 4; ++ni) {
            const int c = col0 + wc + ni * 16 + frow;
            const float bv = bias[c];
            const size_t rbase = row0 + wr + mi * 16 + quad * 4;
#pragma unroll
            for (int reg = 0; reg < 4; ++reg)
                C[(rbase + reg) * 512 + c] = acc[mi][ni][reg] + bv;
        }
    }
}

extern "C" void kernel_launch(void* const* d_in, const int* in_sizes, int n_in,
                              void* d_out, int out_size, void* d_ws, size_t ws_size,
                              hipStream_t stream)
{
    const float* x    = (const float*)d_in[0];   // [65536, 512] fp32
    const float* Wqkv = (const float*)d_in[1];   // [1536, 512]  fp32
    const float* Wout = (const float*)d_in[2];   // [512, 512]   fp32
    const float* bout = (const float*)d_in[3];   // [512]        fp32
    float* out = (float*)d_out;                  // [65536, 512] fp32
    char* ws = (char*)d_ws;

    u16*   wq_bf  = (u16*)ws;                      //   1,572,864 B
    u16*   wo_bf  = (u16*)(ws + 1572864ull);       //     524,288 B
    u16*   wsq    = (u16*)(ws + 2097152ull);       //  67,108,864 B
    u16*   xb     = (u16*)(ws + 69206016ull);      //  67,108,864 B (P reuses this)
    u16*   P      = xb;                            //   8,388,608 B (after gemm_qkv)
    float* kvglob = (float*)(ws + 136314880ull);   //   2,621,440 B
    u16*   ksum   = (u16*)(ws + 138936320ull);     //      65,536 B -> 139,001,856

    // 0) x -> bf16, weights -> bf16 (W_qkv row-permuted), zero kv accumulator
    convert_all<<<17216, 256, 0, stream>>>(x, Wqkv, Wout, xb, wq_bf, wo_bf, kvglob);
    // 1) fused qkv GEMM: q' -> wsq ; per-head kv outer-product -> kvglob
    gemm_qkv<<<dim3(12, 512), 256, 0, stream>>>(xb, wq_bf, wsq, kvglob);
    // 2) P_b = kv_h @ Wout_h (per bh) ; extract ksum  (xb is dead -> P reuses it)
    make_P<<<128, 256, 0, stream>>>(kvglob, wo_bf, P, ksum);
    // 3) q' *= z (per token/head scalar), in place
    apply_z<<<1024, 256, 0, stream>>>(wsq, ksum);
    // 4) out = q'' @ P_b^T + b_out -> d_out (fp32)
    gemm_final<<<dim3(4, 512), 256, 0, stream>>>(wsq, P, out, bout);
}

// Round 7
// 478.124 us; speedup vs baseline: 1.1585x; 1.0645x over previous
//
#include <hip/hip_runtime.h>

// LinearAttention: b=16, n=4096, dim=512, H=8, D=64, inner=512. T=65536 tokens.
// I/O dtype: fp32 (per reference). Compute: bf16 MFMA, fp32 accumulate.
//
// Algebraic form: out[t] = sum_h z_h(t) * (q'_h[t] @ kv_h) @ Wout_h
//                        = (z .* q') @ Pcat,  Pcat_b[c][h*64+d] = sum_e kv_h[d][e] Wout[c][h*64+e]
//
// ws layout (~139 MiB):
//   wq_bf  [1536x512 bf16]  W_qkv converted + ROW-PERMUTED (q | per-head k|v)
//   wo_bf  [ 512x512 bf16]  converted W_out
//   wsq    [65536x512 bf16] q' = act(x@Wq^T); scaled in place by apply_z
//   xb     [65536x512 bf16] x converted once; REUSED as P after gemm_qkv
//   kvglob [128 x 64x80 f32] kv accumulator (atomicAdd), col e=64 = ksum
//   ksum_bf[128 x 64 bf16]  per-(b,h) k-sum vector
//
// NOTE (R6 post-mortem): counted-vmcnt + raw s_barrier pipeline RACED
// (nondeterministic absmax up to 468). Both GEMMs are back on the proven
// 2-phase __syncthreads double-buffer (passed R3+R5, absmax 4.88e-4).

typedef unsigned short u16;
typedef u16 u16x4 __attribute__((ext_vector_type(4)));
typedef u16 u16x8 __attribute__((ext_vector_type(8)));
typedef __bf16 bf16x8 __attribute__((ext_vector_type(8)));
typedef float f32x4 __attribute__((ext_vector_type(4)));

__device__ __forceinline__ float bf2f(u16 x) {
    union { unsigned u; float f; } t; t.u = ((unsigned)x) << 16; return t.f;
}
__device__ __forceinline__ u16 f2bf(float f) {
    union { float f; unsigned u; } t; t.f = f;
    unsigned r = t.u + 0x7fffu + ((t.u >> 16) & 1u);   // RNE
    return (u16)(r >> 16);
}
__device__ __forceinline__ float act_fn(float v) {     // 1 + elu
    return v > 0.0f ? v + 1.0f : __expf(v);
}
__device__ __forceinline__ void cvt8(const float* __restrict__ s, u16* __restrict__ d) {
    f32x4 lo = *(const f32x4*)s;
    f32x4 hi = *(const f32x4*)(s + 4);
    u16x8 o = { f2bf(lo[0]), f2bf(lo[1]), f2bf(lo[2]), f2bf(lo[3]),
                f2bf(hi[0]), f2bf(hi[1]), f2bf(hi[2]), f2bf(hi[3]) };
    *(u16x8*)d = o;
}
// async global->LDS, 16B per lane. LDS dest = wave-uniform base + lane*16.
__device__ __forceinline__ void gld16(const u16* g, u16* l) {
    __builtin_amdgcn_global_load_lds(
        (__attribute__((address_space(1))) const void*)g,
        (__attribute__((address_space(3))) void*)l, 16, 0, 0);
}

// ---------------------------------------------------------------------------
// convert_all: x (4,194,304 x8 units) -> xb ; W_qkv (98,304 units) -> wq_bf
// with the head-interleaved row permutation ; W_out (32,768) -> wo_bf ;
// zero kvglob (81,920 f32 = 10,240 x8 units). 17,216 x 256 exact.
// ---------------------------------------------------------------------------
__global__ __launch_bounds__(256) void convert_all(const float* __restrict__ x,
                                                   const float* __restrict__ Wqkv,
                                                   const float* __restrict__ Wout,
                                                   u16* __restrict__ xb,
                                                   u16* __restrict__ wq,
                                                   u16* __restrict__ wo,
                                                   float* __restrict__ kvg)
{
    size_t u = (size_t)blockIdx.x * 256 + threadIdx.x;
    if (u < 4194304ull) {
        cvt8(x + u * 8, xb + u * 8);
    } else if (u < 4292608ull) {
        u -= 4194304ull;                       // dest unit within wq_bf
        const int drow = (int)(u >> 6);
        int srow;
        if (drow < 512) srow = drow;
        else {
            const int t = drow - 512, h = t >> 7, j = t & 127;
            srow = (j < 64) ? (512 + h * 64 + j) : (1024 + h * 64 + (j - 64));
        }
        cvt8(Wqkv + (size_t)srow * 512 + (u & 63) * 8, wq + u * 8);
    } else if (u < 4325376ull) {
        u -= 4292608ull; cvt8(Wout + u * 8, wo + u * 8);
    } else {
        u -= 4325376ull;
        f32x4 z = { 0.f, 0.f, 0.f, 0.f };
        *(f32x4*)&kvg[u * 8] = z;
        *(f32x4*)&kvg[u * 8 + 4] = z;
    }
}

// ---------------------------------------------------------------------------
// gemm_qkv: C128x128 tile of x @ Wqkv_perm^T, K=512, 2-phase double-buffered
// global_load_lds staging (PROVEN structure: stage next tile, compute, one
// __syncthreads per K-step).
// Col-tiles 0..3 -> q: act + store to wsq.  Col-tiles 4..11 -> head h=nt-4:
// cols 0..63 = k, 64..127 = v; transpose to KT/VT (overlaying the dead LDS
// double buffer), kv[d][e] += KT@VT^T (VT row 64 = ones -> e=64 = ksum),
// atomicAdd into kvglob[b*8+h].
// ---------------------------------------------------------------------------
__global__ __launch_bounds__(256) void gemm_qkv(const u16* __restrict__ A,
                                                const u16* __restrict__ Bw,
                                                u16* __restrict__ Cq,
                                                float* __restrict__ kvglob)
{
    __shared__ u16 SMF[16384];     // 32 KB: buf b at b*8192 (As 4096 | Bs 4096)
    const int nt = blockIdx.x;     // 0..11 col-tile
    const int mt = blockIdx.y;     // 0..511 M-tile
    const size_t row0 = (size_t)mt * 128;
    const int col0 = nt * 128;
    const int tid = threadIdx.x, wave = tid >> 6, lane = tid & 63;
    const int frow = lane & 15, quad = lane >> 4;
    const int wr = (wave >> 1) * 64, wc = (wave & 1) * 64;

    f32x4 acc[4][4] = {};

    // staging: chunk ch = issue*256 + wave*64 + lane; row = ch>>2, col=(ch&3)*8
    const int ch0 = wave * 64 + lane, ch1 = 256 + ch0;
    const int r0 = ch0 >> 2, c0 = (ch0 & 3) * 8;
    const int r1 = ch1 >> 2, c1 = (ch1 & 3) * 8;
    const u16* gA0 = A + (row0 + r0) * 512 + c0;
    const u16* gA1 = A + (row0 + r1) * 512 + c1;
    const u16* gB0 = Bw + (size_t)(col0 + r0) * 512 + c0;
    const u16* gB1 = Bw + (size_t)(col0 + r1) * 512 + c1;

#define QKV_STAGE(buf, k0) do {                                   \
        u16* As_ = SMF + (buf) * 8192;                            \
        u16* Bs_ = As_ + 4096;                                    \
        gld16(gA0 + (k0), As_ + wave * 512);                      \
        gld16(gA1 + (k0), As_ + 2048 + wave * 512);               \
        gld16(gB0 + (k0), Bs_ + wave * 512);                      \
        gld16(gB1 + (k0), Bs_ + 2048 + wave * 512);               \
    } while (0)

    QKV_STAGE(0, 0);
    __syncthreads();               // implicit vmcnt(0): buf0 ready
    int cur = 0;
    for (int t = 0; t < 16; ++t) {
        if (t < 15) QKV_STAGE(cur ^ 1, (t + 1) * 32);   // prefetch next tile
        const u16* As_ = SMF + cur * 8192;
        const u16* Bs_ = As_ + 4096;
        bf16x8 af[4], bfr[4];
#pragma unroll
        for (int mi = 0; mi < 4; ++mi)
            af[mi] = *(const bf16x8*)&As_[(wr + mi * 16 + frow) * 32 + quad * 8];
#pragma unroll
        for (int ni = 0; ni < 4; ++ni)
            bfr[ni] = *(const bf16x8*)&Bs_[(wc + ni * 16 + frow) * 32 + quad * 8];
#pragma unroll
        for (int mi = 0; mi < 4; ++mi)
#pragma unroll
            for (int ni = 0; ni < 4; ++ni)
                acc[mi][ni] = __builtin_amdgcn_mfma_f32_16x16x32_bf16(af[mi], bfr[ni], acc[mi][ni], 0, 0, 0);
        __syncthreads();           // drains vmcnt(0): prefetched buf ready
        cur ^= 1;
    }
#undef QKV_STAGE

    if (col0 < 512) {
        // q epilogue: C/D layout col = lane&15, row = quad*4 + reg [m89/m91]
#pragma unroll
        for (int mi = 0; mi < 4; ++mi) {
#pragma unroll
            for (int ni = 0; ni < 4; ++ni) {
                const int c = col0 + wc + ni * 16 + frow;
                const size_t rbase = row0 + wr + mi * 16 + quad * 4;
#pragma unroll
                for (int reg = 0; reg < 4; ++reg)
                    Cq[(rbase + reg) * 512 + c] = f2bf(act_fn(acc[mi][ni][reg]));
            }
        }
        return;
    }

    // ---- kv epilogue (head h = nt-4), KT/VT overlay the dead double buffer.
    // Safe: final loop iteration ends with __syncthreads(), so all reads of
    // the buffers completed before these writes.
    u16* KT = SMF;                 // [64][72] k^T
    u16* VT = SMF + 4608;          // [80][72] v^T; row 64 = ones
    for (int i = tid; i < 16 * 72; i += 256)
        VT[64 * 72 + i] = (i < 64) ? (u16)0x3F80 : (u16)0;

    const bool is_k = (wc == 0);
    f32x4 kvacc[5] = {};           // e-tiles; d = wave*16 + quad*4 + reg

#pragma unroll
    for (int half = 0; half < 2; ++half) {
        __syncthreads();           // prior KT/VT readers (and ones writes) done
        if ((wave >> 1) == half) { // this wave's tokens belong to this half
#pragma unroll
            for (int mi = 0; mi < 4; ++mi) {
                const int n0 = wr + mi * 16 + quad * 4 - half * 64;   // 0..60
#pragma unroll
                for (int ni = 0; ni < 4; ++ni) {
                    const int cl = wc + ni * 16 + frow;               // 0..127
                    u16x4 o2;
#pragma unroll
                    for (int reg = 0; reg < 4; ++reg) {
                        float v = acc[mi][ni][reg];
                        if (is_k) v = act_fn(v);
                        o2[reg] = f2bf(v);
                    }
                    if (is_k) *(u16x4*)&KT[cl * 72 + n0] = o2;
                    else      *(u16x4*)&VT[(cl - 64) * 72 + n0] = o2;
                }
            }
        }
        __syncthreads();
        // kv[d][e] += KT@VT^T over this half's 64 tokens (2 K-chunks of 32)
#pragma unroll
        for (int c = 0; c < 2; ++c) {
            bf16x8 af2 = *(const bf16x8*)&KT[(wave * 16 + frow) * 72 + c * 32 + quad * 8];
#pragma unroll
            for (int et = 0; et < 5; ++et) {
                bf16x8 bf2 = *(const bf16x8*)&VT[(et * 16 + frow) * 72 + c * 32 + quad * 8];
                kvacc[et] = __builtin_amdgcn_mfma_f32_16x16x32_bf16(af2, bf2, kvacc[et], 0, 0, 0);
            }
        }
    }

    const int b = mt >> 5, h = nt - 4;
    float* dst = kvglob + (size_t)(b * 8 + h) * 5120;
#pragma unroll
    for (int et = 0; et < 5; ++et) {
        const int e = et * 16 + frow;
        if (e <= 64) {
#pragma unroll
            for (int reg = 0; reg < 4; ++reg) {
                const int d = wave * 16 + quad * 4 + reg;
                atomicAdd(&dst[d * 80 + e], kvacc[et][reg]);
            }
        }
    }
}

// ---------------------------------------------------------------------------
// make_P: one block per (b,h). P_b[c][h*64+d] = sum_e Wout[c][h*64+e]*kv[d][e]
// via MFMA (A = Wout rows from global, L2-resident; B = kv rows from LDS).
// Also extracts ksum_bf[bh][d] = kvglob col e=64. 512x64x64 GEMM per block.
// ---------------------------------------------------------------------------
__global__ __launch_bounds__(256) void make_P(const float* __restrict__ kvglob,
                                              const u16* __restrict__ wo,
                                              u16* __restrict__ P,
                                              u16* __restrict__ ksum)
{
    __shared__ u16 kvb[64 * 72];   // kv[d][e] bf16, pad 72
    const int bh = blockIdx.x, b = bh >> 3, h = bh & 7;
    const int tid = threadIdx.x, wave = tid >> 6, lane = tid & 63;
    const int frow = lane & 15, quad = lane >> 4;
    const float* src = kvglob + (size_t)bh * 5120;

    for (int i = tid; i < 4096; i += 256)
        kvb[(i >> 6) * 72 + (i & 63)] = f2bf(src[(i >> 6) * 80 + (i & 63)]);
    if (tid < 64) ksum[bh * 64 + tid] = f2bf(src[tid * 80 + 64]);
    __syncthreads();

    f32x4 acc[8][4] = {};          // m = Wout-row tile (wave*128..+128), n = d
    const int m0 = wave * 128;
#pragma unroll
    for (int k2 = 0; k2 < 2; ++k2) {           // e-chunk of 32
        bf16x8 bfr[4];
#pragma unroll
        for (int ni = 0; ni < 4; ++ni)
            bfr[ni] = *(const bf16x8*)&kvb[(ni * 16 + frow) * 72 + k2 * 32 + quad * 8];
#pragma unroll
        for (int mi = 0; mi < 8; ++mi) {
            bf16x8 af = *(const bf16x8*)&wo[(size_t)(m0 + mi * 16 + frow) * 512 + h * 64 + k2 * 32 + quad * 8];
#pragma unroll
            for (int ni = 0; ni < 4; ++ni)
                acc[mi][ni] = __builtin_amdgcn_mfma_f32_16x16x32_bf16(af, bfr[ni], acc[mi][ni], 0, 0, 0);
        }
    }

    u16* Pb = P + (size_t)b * 262144;
#pragma unroll
    for (int mi = 0; mi < 8; ++mi) {
#pragma unroll
        for (int ni = 0; ni < 4; ++ni) {
            const int d = ni * 16 + frow;      // C/D: col = lane&15
#pragma unroll
            for (int reg = 0; reg < 4; ++reg) {
                const int c = m0 + mi * 16 + quad * 4 + reg;
                Pb[(size_t)c * 512 + h * 64 + d] = f2bf(acc[mi][ni][reg]);
            }
        }
    }
}

// ---------------------------------------------------------------------------
// apply_z: q''[t][i] = q'[t][i] / max(q'_h(t)·ksum_h, eps), h = i/64.
// COALESCED: one wave per token row — 64 lanes x 16B = the whole 1KB row;
// per-head denominator via 3-step shfl_xor within 8-lane groups; lane's
// ksum slice (8 cols) held in regs for the whole block. 1024 blocks x 256,
// 64 tokens/block (batch-aligned), 16 tokens/wave. Race-free: each wave
// owns its rows exclusively (read-modify-write, no cross-wave data).
// ---------------------------------------------------------------------------
__global__ __launch_bounds__(256) void apply_z(u16* __restrict__ qio,
                                               const u16* __restrict__ ksum)
{
    const int tid = threadIdx.x, wave = tid >> 6, lane = tid & 63;
    const int t0 = blockIdx.x * 64 + wave * 16;
    const int b = blockIdx.x >> 6;             // 64 blocks per batch

    u16x8 k8 = *(const u16x8*)&ksum[b * 512 + lane * 8];
    float kf[8];
#pragma unroll
    for (int e = 0; e < 8; ++e) kf[e] = bf2f(k8[e]);

    for (int it = 0; it < 16; ++it) {
        u16* row = qio + (size_t)(t0 + it) * 512 + lane * 8;
        u16x8 q8 = *(const u16x8*)row;
        float den = 0.f;
#pragma unroll
        for (int e = 0; e < 8; ++e) den += bf2f(q8[e]) * kf[e];
        den += __shfl_xor(den, 1);
        den += __shfl_xor(den, 2);
        den += __shfl_xor(den, 4);             // all 8 lanes of head group
        const float z = 1.0f / fmaxf(den, 1e-4f);
        u16x8 o;
#pragma unroll
        for (int e = 0; e < 8; ++e) o[e] = f2bf(bf2f(q8[e]) * z);
        *(u16x8*)row = o;
    }
}

// ---------------------------------------------------------------------------
// gemm_final: out[t][c] (fp32) = sum_i q''[t][i] * P_b[c][i] + bias[c].
// B matrix is per-batch (b = mt>>5), 512 KB, L2-resident. PROVEN 2-phase
// dbuf global_load_lds staging (same as gemm_qkv).
// ---------------------------------------------------------------------------
__global__ __launch_bounds__(256) void gemm_final(const u16* __restrict__ A,
                                                  const u16* __restrict__ P,
                                                  float* __restrict__ C,
                                                  const float* __restrict__ bias)
{
    __shared__ u16 SMF[16384];
    const int nt = blockIdx.x;     // 0..3 col-tile
    const int mt = blockIdx.y;     // 0..511 M-tile
    const size_t row0 = (size_t)mt * 128;
    const int col0 = nt * 128;
    const u16* Bw = P + (size_t)(mt >> 5) * 262144;
    const int tid  = threadIdx.x;
    const int wave = tid >> 6, lane = tid & 63;
    const int wr = (wave >> 1) * 64, wc = (wave & 1) * 64;
    const int frow = lane & 15, quad = lane >> 4;

    f32x4 acc[4][4] = {};

    const int ch0 = wave * 64 + lane, ch1 = 256 + ch0;
    const int r0 = ch0 >> 2, c0 = (ch0 & 3) * 8;
    const int r1 = ch1 >> 2, c1 = (ch1 & 3) * 8;
    const u16* gA0 = A + (row0 + r0) * 512 + c0;
    const u16* gA1 = A + (row0 + r1) * 512 + c1;
    const u16* gB0 = Bw + (size_t)(col0 + r0) * 512 + c0;
    const u16* gB1 = Bw + (size_t)(col0 + r1) * 512 + c1;

#define OUT_STAGE(buf, k0) do {                                   \
        u16* As_ = SMF + (buf) * 8192;                            \
        u16* Bs_ = As_ + 4096;                                    \
        gld16(gA0 + (k0), As_ + wave * 512);                      \
        gld16(gA1 + (k0), As_ + 2048 + wave * 512);               \
        gld16(gB0 + (k0), Bs_ + wave * 512);                      \
        gld16(gB1 + (k0), Bs_ + 2048 + wave * 512);               \
    } while (0)

    OUT_STAGE(0, 0);
    __syncthreads();
    int cur = 0;
    for (int t = 0; t < 16; ++t) {
        if (t < 15) OUT_STAGE(cur ^ 1, (t + 1) * 32);
        const u16* As_ = SMF + cur * 8192;
        const u16* Bs_ = As_ + 4096;
        bf16x8 af[4], bfr[4];
#pragma unroll
        for (int mi = 0; mi < 4; ++mi)
            af[mi] = *(const bf16x8*)&As_[(wr + mi * 16 + frow) * 32 + quad * 8];
#pragma unroll
        for (int ni = 0; ni < 4; ++ni)
            bfr[ni] = *(const bf16x8*)&Bs_[(wc + ni * 16 + frow) * 32 + quad * 8];
#pragma unroll
        for (int mi = 0; mi < 4; ++mi)
#pragma unroll
            for (int ni = 0; ni < 4; ++ni)
                acc[mi][ni] = __builtin_amdgcn_mfma_f32_16x16x32_bf16(af[mi], bfr[ni], acc[mi][ni], 0, 0, 0);
        __syncthreads();
        cur ^= 1;
    }
#undef OUT_STAGE

#pragma unroll
    for (int mi = 0; mi < 4; ++mi) {
#pragma unroll
        for (int ni = 0; ni < 4; ++ni) {
            const int c = col0 + wc + ni * 16 + frow;
            const float bv = bias[c];
            const size_t rbase = row0 + wr + mi * 16 + quad * 4;
#pragma unroll
            for (int reg = 0; reg < 4; ++reg)
                C[(rbase + reg) * 512 + c] = acc[mi][ni][reg] + bv;
        }
    }
}

extern "C" void kernel_launch(void* const* d_in, const int* in_sizes, int n_in,
                              void* d_out, int out_size, void* d_ws, size_t ws_size,
                              hipStream_t stream)
{
    const float* x    = (const float*)d_in[0];   // [65536, 512] fp32
    const float* Wqkv = (const float*)d_in[1];   // [1536, 512]  fp32
    const float* Wout = (const float*)d_in[2];   // [512, 512]   fp32
    const float* bout = (const float*)d_in[3];   // [512]        fp32
    float* out = (float*)d_out;                  // [65536, 512] fp32
    char* ws = (char*)d_ws;

    u16*   wq_bf  = (u16*)ws;                      //   1,572,864 B
    u16*   wo_bf  = (u16*)(ws + 1572864ull);       //     524,288 B
    u16*   wsq    = (u16*)(ws + 2097152ull);       //  67,108,864 B
    u16*   xb     = (u16*)(ws + 69206016ull);      //  67,108,864 B (P reuses this)
    u16*   P      = xb;                            //   8,388,608 B (after gemm_qkv)
    float* kvglob = (float*)(ws + 136314880ull);   //   2,621,440 B
    u16*   ksum   = (u16*)(ws + 138936320ull);     //      65,536 B -> 139,001,856

    // 0) x -> bf16, weights -> bf16 (W_qkv row-permuted), zero kv accumulator
    convert_all<<<17216, 256, 0, stream>>>(x, Wqkv, Wout, xb, wq_bf, wo_bf, kvglob);
    // 1) fused qkv GEMM: q' -> wsq ; per-head kv outer-product -> kvglob
    gemm_qkv<<<dim3(12, 512), 256, 0, stream>>>(xb, wq_bf, wsq, kvglob);
    // 2) P_b = kv_h @ Wout_h (per bh) ; extract ksum  (xb dead -> P reuses it)
    make_P<<<128, 256, 0, stream>>>(kvglob, wo_bf, P, ksum);
    // 3) q' *= z (per token/head scalar), in place — coalesced wave-per-token
    apply_z<<<1024, 256, 0, stream>>>(wsq, ksum);
    // 4) out = q'' @ P_b^T + b_out -> d_out (fp32)
    gemm_final<<<dim3(4, 512), 256, 0, stream>>>(wsq, P, out, bout);
}